// Round 11
// baseline (171.609 us; speedup 1.0000x reference)
//
#include <hip/hip_runtime.h>
#include <climits>

#define VOXD 25
#define SLOT3 (VOXD*VOXD*VOXD)      // 15625
#define SLOTS (2*SLOT3)             // 31250
#define NCLS 8
#define NCODE 16
#define NBLK ((SLOTS + 255) / 256)  // 123
#define HB 2048                     // radix bins (11 bits)
#define FBK 64                      // fallback blocks per code
#define GSZ 16                      // threads per miss point
#define MPB (256 / GSZ)             // misses per block pass = 16
#define CSTRIDE SLOT3               // per-code bucket capacity

struct Scalars {
  double hub;
  double cosSum;
  int n1;
  int nmd;
  int binA, rA, binB, rB;
  float thresh;
  int done;
};

__device__ __forceinline__ int voxslot(int b, int vx, int vy, int vz) {
  return ((b * VOXD + vx) * VOXD + vy) * VOXD + vz;
}

// ---- block-wide inclusive scan (int), 1024 threads = 16 waves ----
__device__ __forceinline__ int block_scan_i(int v, int* ws, int* total) {
  int lane = threadIdx.x & 63, w = threadIdx.x >> 6;
  int s = v;
  #pragma unroll
  for (int off = 1; off < 64; off <<= 1) {
    int t = __shfl_up(s, off, 64);
    if (lane >= off) s += t;
  }
  if (lane == 63) ws[w] = s;
  __syncthreads();
  if (threadIdx.x < 16) {
    int x = ws[threadIdx.x];
    #pragma unroll
    for (int off = 1; off < 16; off <<= 1) {
      int t = __shfl_up(x, off, 64);
      if (lane >= off) x += t;
    }
    ws[threadIdx.x] = x;
  }
  __syncthreads();
  if (w > 0) s += ws[w - 1];
  *total = ws[15];
  __syncthreads();
  return s;
}

// ---------------- K2: per-point scatter; label bitmask; LDS-agg (b,l) stats ------
__global__ void k_scatter(const float* __restrict__ grid, const int* __restrict__ label,
                          const int* __restrict__ batch,
                          int* cnt, float* sx, float* sy, float* sz, int* lmask,
                          int* blCnt, float* blSum, int n) {
  __shared__ int sCnt[NCODE];
  __shared__ float sSum[3 * NCODE];
  int tid = threadIdx.x;
  if (tid < NCODE) sCnt[tid] = 0;
  if (tid < 3 * NCODE) sSum[tid] = 0.f;
  __syncthreads();
  int i = blockIdx.x * blockDim.x + tid;
  if (i < n) {
    float gx = grid[3*i], gy = grid[3*i+1], gz = grid[3*i+2];
    int vx = (int)floorf(gx * (1.0f/16.0f));
    int vy = (int)floorf(gy * (1.0f/16.0f));
    int vz = (int)floorf(gz * (1.0f/16.0f));
    int b = batch[i], l = label[i];
    int s = voxslot(b, vx, vy, vz);
    atomicAdd(&cnt[s], 1);
    atomicAdd(&sx[s], gx); atomicAdd(&sy[s], gy); atomicAdd(&sz[s], gz);
    atomicOr(&lmask[s], 1 << l);
    int bl = b * NCLS + l;
    atomicAdd(&sCnt[bl], 1);
    atomicAdd(&sSum[3*bl], gx); atomicAdd(&sSum[3*bl+1], gy); atomicAdd(&sSum[3*bl+2], gz);
  }
  __syncthreads();
  if (tid < NCODE && sCnt[tid] != 0) atomicAdd(&blCnt[tid], sCnt[tid]);
  if (tid < 3 * NCODE && sSum[tid] != 0.f) atomicAdd(&blSum[tid], sSum[tid]);
}

// ---------------- K3: slot table float4 + direct per-code bucket append ----------
__global__ void k_prep(const int* cnt, const float* sx, const float* sy, const float* sz,
                       const int* lmask, float4* ctr, float4* pC, int* pSlot,
                       int* codeCnt) {
  __shared__ int lc[NCODE];
  __shared__ int lb[NCODE];
  int tid = threadIdx.x;
  if (tid < NCODE) lc[tid] = 0;
  __syncthreads();
  int s = blockIdx.x * 256 + tid;
  int code = -1, lpos = 0;
  float4 v = make_float4(0.f, 0.f, 0.f, __int_as_float(-2));
  if (s < SLOTS) {
    int c = cnt[s];
    if (c > 0) {
      float fc = (float)c;
      float cx = __fdiv_rn(sx[s], fc);
      float cy = __fdiv_rn(sy[s], fc);
      float cz = __fdiv_rn(sz[s], fc);
      int m = lmask[s];
      bool pure = (m & (m - 1)) == 0;
      int lbl = __ffs(m) - 1;
      v = make_float4(cx, cy, cz, __int_as_float(pure ? lbl : -1));
      if (pure) {
        code = (s / SLOT3) * NCLS + lbl;
        lpos = atomicAdd(&lc[code], 1);
      }
    }
    ctr[s] = v;
  }
  __syncthreads();
  if (tid < NCODE) lb[tid] = (lc[tid] > 0) ? atomicAdd(&codeCnt[tid], lc[tid]) : 0;
  __syncthreads();
  if (code >= 0) {
    int pos = code * CSTRIDE + lb[code] + lpos;
    float c2 = __fadd_rn(__fadd_rn(__fmul_rn(v.x,v.x), __fmul_rn(v.y,v.y)),
                         __fmul_rn(v.z,v.z));
    pC[pos] = make_float4(v.x, v.y, v.z, c2);
    pSlot[pos] = s;
  }
}

// ---------------- K5: probe targets + per-code miss lists + LDS hist -------------
__global__ void k_targets(const float* __restrict__ grid, const int* __restrict__ label,
                          const int* __restrict__ batch,
                          const float4* __restrict__ ctr,
                          const int* __restrict__ blCnt, const float* __restrict__ blSum,
                          float* tgt, float* mag, int* ghist,
                          int* missPart, int* missCnt, int mstride, int n) {
  __shared__ int wCnt[4][NCODE];
  __shared__ int gBase[NCODE];
  __shared__ int h[HB];
  int tid = threadIdx.x, lane = tid & 63, w = tid >> 6;
  for (int t = tid; t < HB; t += 256) h[t] = 0;
  __syncthreads();
  int i = blockIdx.x * blockDim.x + tid;
  bool active = (i < n);
  bool miss = false;
  int mcode = -1;

  if (active) {
    float gx = grid[3*i], gy = grid[3*i+1], gz = grid[3*i+2];
    int vx = (int)floorf(gx * (1.0f/16.0f));
    int vy = (int)floorf(gy * (1.0f/16.0f));
    int vz = (int)floorf(gz * (1.0f/16.0f));
    int b = batch[i], l = label[i];
    int s = voxslot(b, vx, vy, vz);

    float4 own = ctr[s];
    bool purept = (__float_as_int(own.w) >= 0);

    int bl = b * NCLS + l;
    float fbc = (float)max(blCnt[bl], 1);
    float gcx = __fdiv_rn(blSum[3*bl],   fbc);
    float gcy = __fdiv_rn(blSum[3*bl+1], fbc);
    float gcz = __fdiv_rn(blSum[3*bl+2], fbc);

    float dx = __fsub_rn(gcx, own.x);
    float dy = __fsub_rn(gcy, own.y);
    float dz = __fsub_rn(gcz, own.z);
    int sgx = (dx > 0.f) ? 1 : ((dx < 0.f) ? -1 : 0);
    int sgy = (dy > 0.f) ? 1 : ((dy < 0.f) ? -1 : 0);
    int sgz = (dz > 0.f) ? 1 : ((dz < 0.f) ? -1 : 0);

    int ax1 = vx + sgx,     ay1 = vy + sgy,     az1 = vz + sgz;
    int ax2 = vx + 2 * sgx, ay2 = vy + 2 * sgy, az2 = vz + 2 * sgz;
    bool v1 = (unsigned)ax1 < (unsigned)VOXD && (unsigned)ay1 < (unsigned)VOXD &&
              (unsigned)az1 < (unsigned)VOXD;
    bool v2 = (unsigned)ax2 < (unsigned)VOXD && (unsigned)ay2 < (unsigned)VOXD &&
              (unsigned)az2 < (unsigned)VOXD;

    float4 q1 = make_float4(0.f, 0.f, 0.f, __int_as_float(-3));
    float4 q2 = q1;
    if (v1) q1 = ctr[voxslot(b, ax1, ay1, az1)];
    if (v2) q2 = ctr[voxslot(b, ax2, ay2, az2)];

    bool hit1 = v1 && (__float_as_int(q1.w) == l);
    bool hit2 = v2 && (__float_as_int(q2.w) == l);
    bool hit = hit1 || hit2;

    float tx = hit1 ? q1.x : (hit2 ? q2.x : gx);
    float ty = hit1 ? q1.y : (hit2 ? q2.y : gy);
    float tz = hit1 ? q1.z : (hit2 ? q2.z : gz);

    tgt[3*i] = tx; tgt[3*i+1] = ty; tgt[3*i+2] = tz;
    miss = (!purept && !hit);
    if (miss) {
      mcode = bl;
    } else {
      float tox = __fsub_rn(tx, gx), toy = __fsub_rn(ty, gy), toz = __fsub_rn(tz, gz);
      float ssq = __fadd_rn(__fadd_rn(__fmul_rn(tox,tox), __fmul_rn(toy,toy)),
                            __fmul_rn(toz,toz));
      float m = (ssq > 0.f) ? sqrtf(ssq) : 0.f;
      mag[i] = m;
      atomicAdd(&h[__float_as_uint(m) >> 21], 1);
    }
  }
  int myrank = 0;
  #pragma unroll
  for (int c = 0; c < NCODE; ++c) {
    unsigned long long mb = __ballot(mcode == c);
    if (lane == 0) wCnt[w][c] = __popcll(mb);
    if (mcode == c) myrank = __popcll(mb & ((1ULL << lane) - 1ULL));
  }
  __syncthreads();
  if (tid < NCODE) {
    int tot = wCnt[0][tid] + wCnt[1][tid] + wCnt[2][tid] + wCnt[3][tid];
    gBase[tid] = (tot > 0) ? atomicAdd(&missCnt[tid], tot) : 0;
  }
  __syncthreads();
  if (miss) {
    int base = gBase[mcode];
    for (int q = 0; q < 4; ++q) if (q < w) base += wCnt[q][mcode];
    missPart[mcode * mstride + base + myrank] = i;
  }
  for (int t = tid; t < HB; t += 256) {
    int c = h[t];
    if (c != 0) atomicAdd(&ghist[t], c);
  }
}

// ---------------- K6: fallback — 16-thread group per miss, LDS tiles + hist ------
__global__ void __launch_bounds__(256) k_fallback(
    const float* __restrict__ grid,
    const float4* __restrict__ pC, const int* __restrict__ pSlot,
    const float4* __restrict__ ctr,
    const int* __restrict__ codeCnt,
    const int* __restrict__ missPart, const int* __restrict__ missCnt,
    float* tgt, float* mag, int* ghist, int mstride) {
  __shared__ float4 tile[1024];
  __shared__ int stile[1024];
  __shared__ int h[HB];
  int c = blockIdx.x / FBK;
  int y = blockIdx.x % FBK;
  int mc = missCnt[c];
  if (y * MPB >= mc) return;           // uniform per block
  int cc = codeCnt[c];
  int j0 = c * CSTRIDE;
  const int* mlist = missPart + c * mstride;
  int g = threadIdx.x >> 4;
  int q = threadIdx.x & (GSZ - 1);
  for (int t = threadIdx.x; t < HB; t += 256) h[t] = 0;

  for (int base = y * MPB; base < mc; base += FBK * MPB) {
    int t = base + g;
    bool valid = (t < mc);
    int idx = 0;
    float gx = 0.f, gy = 0.f, gz = 0.f, p2 = 0.f;
    if (valid) {
      idx = mlist[t];
      gx = grid[3*idx]; gy = grid[3*idx+1]; gz = grid[3*idx+2];
      p2 = __fadd_rn(__fadd_rn(__fmul_rn(gx,gx), __fmul_rn(gy,gy)), __fmul_rn(gz,gz));
    }
    unsigned long long key = 0xFFFFFFFFFFFFFFFFULL;
    for (int tb = 0; tb < cc; tb += 1024) {
      int m = min(1024, cc - tb);
      __syncthreads();
      for (int j = threadIdx.x; j < m; j += 256) {
        tile[j] = pC[j0 + tb + j];
        stile[j] = pSlot[j0 + tb + j];
      }
      __syncthreads();
      if (valid) {
        for (int j = q; j < m; j += GSZ) {
          float4 cl = tile[j];
          float dot = __fadd_rn(__fadd_rn(__fmul_rn(gx,cl.x), __fmul_rn(gy,cl.y)),
                                __fmul_rn(gz,cl.z));
          float d2 = __fadd_rn(__fsub_rn(p2, __fmul_rn(2.0f, dot)), cl.w);
          unsigned fb = __float_as_uint(d2);
          fb = (fb >> 31) ? ~fb : (fb | 0x80000000u);
          unsigned long long k2 = ((unsigned long long)fb << 32) | (unsigned)stile[j];
          if (k2 < key) key = k2;
        }
      }
    }
    #pragma unroll
    for (int off = 1; off < GSZ; off <<= 1) {
      unsigned long long o = __shfl_xor(key, off, 64);
      if (o < key) key = o;
    }
    if (valid && q == 0) {
      float m = 0.f;
      if (cc > 0) {
        int slot = (int)(unsigned)(key & 0xFFFFFFFFULL);
        float4 cl = ctr[slot];
        tgt[3*idx] = cl.x; tgt[3*idx+1] = cl.y; tgt[3*idx+2] = cl.z;
        float tox = __fsub_rn(cl.x, gx), toy = __fsub_rn(cl.y, gy), toz = __fsub_rn(cl.z, gz);
        float ssq = __fadd_rn(__fadd_rn(__fmul_rn(tox,tox), __fmul_rn(toy,toy)),
                              __fmul_rn(toz,toz));
        m = (ssq > 0.f) ? sqrtf(ssq) : 0.f;
      }
      mag[idx] = m;
      atomicAdd(&h[__float_as_uint(m) >> 21], 1);
    }
    __syncthreads();
  }
  for (int t = threadIdx.x; t < HB; t += 256) {
    int cv = h[t];
    if (cv != 0) atomicAdd(&ghist[t], cv);
  }
}

// ---------------- K7: gather with inlined coarse-bin selection -------------------
// Every block recomputes (binA,rA,binB,rB) from ghist (identical values);
// block 0 publishes them to sc for k_sel.
__global__ void k_gather(const float* __restrict__ mag, const int* __restrict__ ghist,
                         Scalars* sc, unsigned* bufA, unsigned* bufB, int* cntAB,
                         int n, int r0, int r1) {
  __shared__ int ws[4];
  __shared__ int sBinA, sRA, sBinB, sRB;
  int tid = threadIdx.x, lane = tid & 63, w = tid >> 6;
  // coarse select: each thread owns 8 consecutive bins
  int base8 = tid * 8;
  int cbin[8];
  int s = 0;
  #pragma unroll
  for (int k = 0; k < 8; ++k) { cbin[k] = ghist[base8 + k]; s += cbin[k]; }
  int incl = s;
  #pragma unroll
  for (int off = 1; off < 64; off <<= 1) {
    int t = __shfl_up(incl, off, 64);
    if (lane >= off) incl += t;
  }
  if (lane == 63) ws[w] = incl;
  __syncthreads();
  int wofs = 0;
  #pragma unroll
  for (int qq = 0; qq < 4; ++qq) if (qq < w) wofs += ws[qq];
  int lo = wofs + incl - s;
  if (r0 >= lo && r0 < lo + s) {
    int acc = lo;
    #pragma unroll
    for (int k = 0; k < 8; ++k) {
      if (r0 < acc + cbin[k]) { sBinA = base8 + k; sRA = r0 - acc; break; }
      acc += cbin[k];
    }
  }
  if (r1 >= lo && r1 < lo + s) {
    int acc = lo;
    #pragma unroll
    for (int k = 0; k < 8; ++k) {
      if (r1 < acc + cbin[k]) { sBinB = base8 + k; sRB = r1 - acc; break; }
      acc += cbin[k];
    }
  }
  __syncthreads();
  if (blockIdx.x == 0 && tid == 0) {
    sc->binA = sBinA; sc->rA = sRA; sc->binB = sBinB; sc->rB = sRB;
  }
  int binA = sBinA, binB = sBinB;

  int i = blockIdx.x * blockDim.x + tid;
  unsigned bits = 0;
  bool inA = false, inB = false;
  if (i < n) {
    bits = __float_as_uint(mag[i]);
    unsigned cb = bits >> 21;
    inA = (cb == (unsigned)binA);
    inB = (cb == (unsigned)binB);
  }
  {
    unsigned long long mb = __ballot(inA);
    int mc = __popcll(mb);
    int bs = 0;
    if (lane == 0 && mc > 0) bs = atomicAdd(&cntAB[0], mc);
    bs = __shfl(bs, 0, 64);
    if (inA) bufA[bs + __popcll(mb & ((1ULL << lane) - 1ULL))] = bits;
  }
  {
    unsigned long long mb = __ballot(inB);
    int mc = __popcll(mb);
    int bs = 0;
    if (lane == 0 && mc > 0) bs = atomicAdd(&cntAB[1], mc);
    bs = __shfl(bs, 0, 64);
    if (inB) bufB[bs + __popcll(mb & ((1ULL << lane) - 1ULL))] = bits;
  }
}

// ---------------- K7d helper: exact rank select within a coarse bin --------------
__device__ unsigned select_in_bin(const unsigned* __restrict__ buf, int cnt,
                                  int coarse, int rank, int* h, int* ws) {
  __shared__ int sSub, sSubR, sLow;
  for (int t = threadIdx.x; t < HB; t += 1024) h[t] = 0;
  __syncthreads();
  for (int t = threadIdx.x; t < cnt; t += 1024)
    atomicAdd(&h[(buf[t] >> 10) & 0x7FF], 1);
  __syncthreads();
  int t = threadIdx.x;
  int s0 = h[2*t], s1 = h[2*t+1];
  int tot;
  int incl = block_scan_i(s0 + s1, ws, &tot);
  int b1 = incl - s1, b0 = b1 - s0;
  if (rank >= b0 && rank < b0 + s0) { sSub = 2*t;   sSubR = rank - b0; }
  if (rank >= b1 && rank < b1 + s1) { sSub = 2*t+1; sSubR = rank - b1; }
  __syncthreads();
  int subv = sSub, subr = sSubR;
  h[t] = 0;
  __syncthreads();
  for (int q = threadIdx.x; q < cnt; q += 1024) {
    unsigned v = buf[q];
    if ((int)((v >> 10) & 0x7FF) == subv) atomicAdd(&h[v & 0x3FF], 1);
  }
  __syncthreads();
  int c = h[t];
  int tot2;
  int incl2 = block_scan_i(c, ws, &tot2);
  int lb = incl2 - c;
  if (subr >= lb && subr < lb + c) sLow = t;
  __syncthreads();
  return ((unsigned)coarse << 21) | ((unsigned)subv << 10) | (unsigned)sLow;
}

// ---------------- K7d: exact order statistics + lerp (numpy branch) --------------
__global__ void __launch_bounds__(1024) k_sel(const unsigned* __restrict__ bufA,
                                              const unsigned* __restrict__ bufB,
                                              const int* __restrict__ cntAB,
                                              Scalars* sc, double tfrac) {
  __shared__ int h[HB];
  __shared__ int ws[16];
  unsigned va = select_in_bin(bufA, cntAB[0], sc->binA, sc->rA, h, ws);
  __syncthreads();
  unsigned vb = select_in_bin(bufB, cntAB[1], sc->binB, sc->rB, h, ws);
  if (threadIdx.x == 0) {
    double a = (double)__uint_as_float(va);
    double b = (double)__uint_as_float(vb);
    double th = (tfrac >= 0.5) ? (b - (b - a) * (1.0 - tfrac)) : (a + (b - a) * tfrac);
    sc->thresh = (float)th;
  }
}

// ---------------- K8: masked huber + cosine reductions + last-block finalize -----
__global__ void k_loss(const float* __restrict__ pred, const float* __restrict__ grid,
                       const float* __restrict__ tgt, const float* __restrict__ mag,
                       Scalars* sc, float* out, int n) {
  __shared__ double shH[256];
  __shared__ double shC[256];
  __shared__ int shN[256];
  __shared__ int shM[256];
  int tid = threadIdx.x;
  int i = blockIdx.x * blockDim.x + tid;
  double hub = 0.0, cs = 0.0;
  int c1 = 0, cmd = 0;
  if (i < n) {
    float th = sc->thresh;
    float m = mag[i];
    if (m <= th) {
      c1 = 1;
      float tox = __fsub_rn(tgt[3*i],   grid[3*i]);
      float toy = __fsub_rn(tgt[3*i+1], grid[3*i+1]);
      float toz = __fsub_rn(tgt[3*i+2], grid[3*i+2]);
      float px = pred[3*i], py = pred[3*i+1], pz = pred[3*i+2];
      float d0 = __fsub_rn(px, tox), d1 = __fsub_rn(py, toy), d2 = __fsub_rn(pz, toz);
      float a0 = fabsf(d0), a1 = fabsf(d1), a2 = fabsf(d2);
      float h0 = (a0 < 1.f) ? __fmul_rn(__fmul_rn(0.5f, d0), d0) : __fsub_rn(a0, 0.5f);
      float h1 = (a1 < 1.f) ? __fmul_rn(__fmul_rn(0.5f, d1), d1) : __fsub_rn(a1, 0.5f);
      float h2 = (a2 < 1.f) ? __fmul_rn(__fmul_rn(0.5f, d2), d2) : __fsub_rn(a2, 0.5f);
      hub = (double)h0 + (double)h1 + (double)h2;
      if (m > 0.f) {
        cmd = 1;
        float ps = __fadd_rn(__fadd_rn(__fmul_rn(px,px), __fmul_rn(py,py)), __fmul_rn(pz,pz));
        float pn = (ps > 0.f) ? sqrtf(ps) : 0.f;
        float dotp = __fadd_rn(__fadd_rn(__fmul_rn(px,tox), __fmul_rn(py,toy)),
                               __fmul_rn(pz,toz));
        float den = fmaxf(__fmul_rn(pn, m), 1e-4f);
        cs = (double)__fdiv_rn(dotp, den);
      }
    }
  }
  shH[tid] = hub; shC[tid] = cs; shN[tid] = c1; shM[tid] = cmd;
  __syncthreads();
  for (int off = 128; off > 0; off >>= 1) {
    if (tid < off) {
      shH[tid] += shH[tid+off];
      shC[tid] += shC[tid+off];
      shN[tid] += shN[tid+off];
      shM[tid] += shM[tid+off];
    }
    __syncthreads();
  }
  if (tid == 0) {
    atomicAdd(&sc->hub, shH[0]);
    atomicAdd(&sc->cosSum, shC[0]);
    atomicAdd(&sc->n1, shN[0]);
    atomicAdd(&sc->nmd, shM[0]);
    __threadfence();
    int d = atomicAdd(&sc->done, 1);
    if (d == (int)gridDim.x - 1) {
      __threadfence();
      double th_hub = atomicAdd(&sc->hub, 0.0);
      double th_cos = atomicAdd(&sc->cosSum, 0.0);
      int n1 = atomicAdd(&sc->n1, 0);
      int nmd = atomicAdd(&sc->nmd, 0);
      double l1 = (n1 > 0) ? th_hub / fmax((double)n1 * 3.0, 1.0) : 0.0;
      double ld = (nmd > 0) ? (1.0 - th_cos / fmax((double)nmd, 1.0)) : 0.0;
      out[0] = (float)l1;
      out[1] = (float)ld;
    }
  }
}

extern "C" void kernel_launch(void* const* d_in, const int* in_sizes, int n_in,
                              void* d_out, int out_size, void* d_ws, size_t ws_size,
                              hipStream_t stream) {
  const float* pred  = (const float*)d_in[0];
  const float* grid  = (const float*)d_in[1];
  const int*   label = (const int*)d_in[2];
  const int*   batch = (const int*)d_in[3];
  int n = in_sizes[2];
  int mstride = n / 4;

  char* p = (char*)d_ws;
  auto take = [&](size_t bytes) -> char* {
    char* r = p;
    p += (bytes + 255) & ~(size_t)255;
    return r;
  };
  // ---- zero-init region (one hipMemsetAsync covers all of it) ----
  char* zbase = p;
  int*    cnt      = (int*)   take((size_t)SLOTS*4);
  float*  sx       = (float*) take((size_t)SLOTS*4);
  float*  sy       = (float*) take((size_t)SLOTS*4);
  float*  sz       = (float*) take((size_t)SLOTS*4);
  int*    lmask    = (int*)   take((size_t)SLOTS*4);
  int*    codeCnt  = (int*)   take(NCODE*4);
  int*    missCnt  = (int*)   take(NCODE*4);
  int*    blCnt    = (int*)   take(16*4);
  float*  blSum    = (float*) take(48*4);
  int*    cntAB    = (int*)   take(2*4);
  int*    ghist    = (int*)   take((size_t)HB*4);
  Scalars* sc      = (Scalars*)take(sizeof(Scalars));
  size_t zbytes = (size_t)(p - zbase);
  // ---- uninitialized buffers ----
  float4* ctr      = (float4*)take((size_t)SLOTS*16);
  float4* pC       = (float4*)take((size_t)NCODE*CSTRIDE*16);
  int*    pSlot    = (int*)   take((size_t)NCODE*CSTRIDE*4);
  unsigned* bufA   = (unsigned*)take((size_t)n*4);
  unsigned* bufB   = (unsigned*)take((size_t)n*4);
  float*  tgt      = (float*) take((size_t)n*3*4);
  float*  mag      = (float*) take((size_t)n*4);
  int*    missPart = (int*)   take((size_t)NCODE*mstride*4);

  int nb = (n + 255) / 256;

  double vi = 0.99 * (double)(n - 1);
  int r0 = (int)vi;
  int r1 = r0 + 1; if (r1 > n - 1) r1 = n - 1;
  double tfrac = vi - (double)r0;

  hipMemsetAsync(zbase, 0, zbytes, stream);
  k_scatter<<<nb, 256, 0, stream>>>(grid, label, batch, cnt, sx, sy, sz, lmask,
                                    blCnt, blSum, n);
  k_prep<<<NBLK, 256, 0, stream>>>(cnt, sx, sy, sz, lmask, ctr, pC, pSlot, codeCnt);
  k_targets<<<nb, 256, 0, stream>>>(grid, label, batch, ctr, blCnt, blSum,
                                    tgt, mag, ghist, missPart, missCnt, mstride, n);
  k_fallback<<<NCODE * FBK, 256, 0, stream>>>(grid, pC, pSlot, ctr, codeCnt,
                                              missPart, missCnt, tgt, mag, ghist,
                                              mstride);
  k_gather<<<nb, 256, 0, stream>>>(mag, ghist, sc, bufA, bufB, cntAB, n, r0, r1);
  k_sel<<<1, 1024, 0, stream>>>(bufA, bufB, cntAB, sc, tfrac);
  k_loss<<<nb, 256, 0, stream>>>(pred, grid, tgt, mag, sc, (float*)d_out, n);
}

// Round 12
// 163.279 us; speedup vs baseline: 1.0510x; 1.0510x over previous
//
#include <hip/hip_runtime.h>
#include <climits>

#define VOXD 25
#define SLOT3 (VOXD*VOXD*VOXD)      // 15625
#define SLOTS (2*SLOT3)             // 31250
#define NCLS 8
#define NCODE 16
#define NBLK ((SLOTS + 255) / 256)  // 123
#define HB 2048                     // radix bins (11 bits)
#define FBK 64                      // fallback blocks per code
#define GSZ 16                      // threads per miss point
#define MPB (256 / GSZ)             // misses per block pass = 16
#define CSTRIDE SLOT3               // per-code bucket capacity

struct Scalars {
  double hub;
  double cosSum;
  int n1;
  int nmd;
  int binA, rA, binB, rB;
  float thresh;
  int done;
};

__device__ __forceinline__ int voxslot(int b, int vx, int vy, int vz) {
  return ((b * VOXD + vx) * VOXD + vy) * VOXD + vz;
}

// ---- block-wide inclusive scan (int), 1024 threads = 16 waves ----
__device__ __forceinline__ int block_scan_i(int v, int* ws, int* total) {
  int lane = threadIdx.x & 63, w = threadIdx.x >> 6;
  int s = v;
  #pragma unroll
  for (int off = 1; off < 64; off <<= 1) {
    int t = __shfl_up(s, off, 64);
    if (lane >= off) s += t;
  }
  if (lane == 63) ws[w] = s;
  __syncthreads();
  if (threadIdx.x < 16) {
    int x = ws[threadIdx.x];
    #pragma unroll
    for (int off = 1; off < 16; off <<= 1) {
      int t = __shfl_up(x, off, 64);
      if (lane >= off) x += t;
    }
    ws[threadIdx.x] = x;
  }
  __syncthreads();
  if (w > 0) s += ws[w - 1];
  *total = ws[15];
  __syncthreads();
  return s;
}

// ---------------- K2: scatter with packed integer-exact atomics ------------------
// vA[s] = [sum_x:32 | sum_y:32] (u64 add); vB[s] = [sum_z:40 | cnt:24] (u64 add);
// lmask[s] = label bitmask (or). Integer sums == reference f32 sums (all < 2^24).
__global__ void k_scatter(const float* __restrict__ grid, const int* __restrict__ label,
                          const int* __restrict__ batch,
                          unsigned long long* vA, unsigned long long* vB, int* lmask,
                          int* blCnt, float* blSum, int n) {
  __shared__ int sCnt[NCODE];
  __shared__ float sSum[3 * NCODE];
  int tid = threadIdx.x;
  if (tid < NCODE) sCnt[tid] = 0;
  if (tid < 3 * NCODE) sSum[tid] = 0.f;
  __syncthreads();
  int i = blockIdx.x * blockDim.x + tid;
  if (i < n) {
    float gx = grid[3*i], gy = grid[3*i+1], gz = grid[3*i+2];
    int ix = (int)gx, iy = (int)gy, iz = (int)gz;   // coords are exact small ints
    int vx = (int)floorf(gx * (1.0f/16.0f));
    int vy = (int)floorf(gy * (1.0f/16.0f));
    int vz = (int)floorf(gz * (1.0f/16.0f));
    int b = batch[i], l = label[i];
    int s = voxslot(b, vx, vy, vz);
    atomicAdd(&vA[s], ((unsigned long long)(unsigned)ix << 32) | (unsigned)iy);
    atomicAdd(&vB[s], ((unsigned long long)(unsigned)iz << 24) | 1ULL);
    atomicOr(&lmask[s], 1 << l);
    int bl = b * NCLS + l;
    atomicAdd(&sCnt[bl], 1);
    atomicAdd(&sSum[3*bl], gx); atomicAdd(&sSum[3*bl+1], gy); atomicAdd(&sSum[3*bl+2], gz);
  }
  __syncthreads();
  if (tid < NCODE && sCnt[tid] != 0) atomicAdd(&blCnt[tid], sCnt[tid]);
  if (tid < 3 * NCODE && sSum[tid] != 0.f) atomicAdd(&blSum[tid], sSum[tid]);
}

// ---------------- K3: decode tables -> slot float4 + per-code bucket append ------
__global__ void k_prep(const unsigned long long* vA, const unsigned long long* vB,
                       const int* lmask, float4* ctr, float4* pC, int* pSlot,
                       int* codeCnt) {
  __shared__ int lc[NCODE];
  __shared__ int lb[NCODE];
  int tid = threadIdx.x;
  if (tid < NCODE) lc[tid] = 0;
  __syncthreads();
  int s = blockIdx.x * 256 + tid;
  int code = -1, lpos = 0;
  float4 v = make_float4(0.f, 0.f, 0.f, __int_as_float(-2));
  if (s < SLOTS) {
    unsigned long long bq = vB[s];
    unsigned c = (unsigned)(bq & 0xFFFFFFULL);
    if (c > 0) {
      unsigned long long aq = vA[s];
      float fc = (float)c;
      float cx = __fdiv_rn((float)(unsigned)(aq >> 32), fc);
      float cy = __fdiv_rn((float)(unsigned)(aq & 0xFFFFFFFFULL), fc);
      float cz = __fdiv_rn((float)(unsigned)(bq >> 24), fc);
      int m = lmask[s];
      bool pure = (m & (m - 1)) == 0;
      int lbl = __ffs(m) - 1;
      v = make_float4(cx, cy, cz, __int_as_float(pure ? lbl : -1));
      if (pure) {
        code = (s / SLOT3) * NCLS + lbl;
        lpos = atomicAdd(&lc[code], 1);
      }
    }
    ctr[s] = v;
  }
  __syncthreads();
  if (tid < NCODE) lb[tid] = (lc[tid] > 0) ? atomicAdd(&codeCnt[tid], lc[tid]) : 0;
  __syncthreads();
  if (code >= 0) {
    int pos = code * CSTRIDE + lb[code] + lpos;
    float c2 = __fadd_rn(__fadd_rn(__fmul_rn(v.x,v.x), __fmul_rn(v.y,v.y)),
                         __fmul_rn(v.z,v.z));
    pC[pos] = make_float4(v.x, v.y, v.z, c2);
    pSlot[pos] = s;
  }
}

// ---------------- K5: probe targets + per-code miss lists + LDS hist -------------
__global__ void k_targets(const float* __restrict__ grid, const int* __restrict__ label,
                          const int* __restrict__ batch,
                          const float4* __restrict__ ctr,
                          const int* __restrict__ blCnt, const float* __restrict__ blSum,
                          float* tgt, float* mag, int* ghist,
                          int* missPart, int* missCnt, int mstride, int n) {
  __shared__ int wCnt[4][NCODE];
  __shared__ int gBase[NCODE];
  __shared__ int h[HB];
  int tid = threadIdx.x, lane = tid & 63, w = tid >> 6;
  for (int t = tid; t < HB; t += 256) h[t] = 0;
  __syncthreads();
  int i = blockIdx.x * blockDim.x + tid;
  bool active = (i < n);
  bool miss = false;
  int mcode = -1;

  if (active) {
    float gx = grid[3*i], gy = grid[3*i+1], gz = grid[3*i+2];
    int vx = (int)floorf(gx * (1.0f/16.0f));
    int vy = (int)floorf(gy * (1.0f/16.0f));
    int vz = (int)floorf(gz * (1.0f/16.0f));
    int b = batch[i], l = label[i];
    int s = voxslot(b, vx, vy, vz);

    float4 own = ctr[s];
    bool purept = (__float_as_int(own.w) >= 0);

    int bl = b * NCLS + l;
    float fbc = (float)max(blCnt[bl], 1);
    float gcx = __fdiv_rn(blSum[3*bl],   fbc);
    float gcy = __fdiv_rn(blSum[3*bl+1], fbc);
    float gcz = __fdiv_rn(blSum[3*bl+2], fbc);

    float dx = __fsub_rn(gcx, own.x);
    float dy = __fsub_rn(gcy, own.y);
    float dz = __fsub_rn(gcz, own.z);
    int sgx = (dx > 0.f) ? 1 : ((dx < 0.f) ? -1 : 0);
    int sgy = (dy > 0.f) ? 1 : ((dy < 0.f) ? -1 : 0);
    int sgz = (dz > 0.f) ? 1 : ((dz < 0.f) ? -1 : 0);

    int ax1 = vx + sgx,     ay1 = vy + sgy,     az1 = vz + sgz;
    int ax2 = vx + 2 * sgx, ay2 = vy + 2 * sgy, az2 = vz + 2 * sgz;
    bool v1 = (unsigned)ax1 < (unsigned)VOXD && (unsigned)ay1 < (unsigned)VOXD &&
              (unsigned)az1 < (unsigned)VOXD;
    bool v2 = (unsigned)ax2 < (unsigned)VOXD && (unsigned)ay2 < (unsigned)VOXD &&
              (unsigned)az2 < (unsigned)VOXD;

    float4 q1 = make_float4(0.f, 0.f, 0.f, __int_as_float(-3));
    float4 q2 = q1;
    if (v1) q1 = ctr[voxslot(b, ax1, ay1, az1)];
    if (v2) q2 = ctr[voxslot(b, ax2, ay2, az2)];

    bool hit1 = v1 && (__float_as_int(q1.w) == l);
    bool hit2 = v2 && (__float_as_int(q2.w) == l);
    bool hit = hit1 || hit2;

    float tx = hit1 ? q1.x : (hit2 ? q2.x : gx);
    float ty = hit1 ? q1.y : (hit2 ? q2.y : gy);
    float tz = hit1 ? q1.z : (hit2 ? q2.z : gz);

    tgt[3*i] = tx; tgt[3*i+1] = ty; tgt[3*i+2] = tz;
    miss = (!purept && !hit);
    if (miss) {
      mcode = bl;
    } else {
      float tox = __fsub_rn(tx, gx), toy = __fsub_rn(ty, gy), toz = __fsub_rn(tz, gz);
      float ssq = __fadd_rn(__fadd_rn(__fmul_rn(tox,tox), __fmul_rn(toy,toy)),
                            __fmul_rn(toz,toz));
      float m = (ssq > 0.f) ? sqrtf(ssq) : 0.f;
      mag[i] = m;
      atomicAdd(&h[__float_as_uint(m) >> 21], 1);
    }
  }
  int myrank = 0;
  #pragma unroll
  for (int c = 0; c < NCODE; ++c) {
    unsigned long long mb = __ballot(mcode == c);
    if (lane == 0) wCnt[w][c] = __popcll(mb);
    if (mcode == c) myrank = __popcll(mb & ((1ULL << lane) - 1ULL));
  }
  __syncthreads();
  if (tid < NCODE) {
    int tot = wCnt[0][tid] + wCnt[1][tid] + wCnt[2][tid] + wCnt[3][tid];
    gBase[tid] = (tot > 0) ? atomicAdd(&missCnt[tid], tot) : 0;
  }
  __syncthreads();
  if (miss) {
    int base = gBase[mcode];
    for (int q = 0; q < 4; ++q) if (q < w) base += wCnt[q][mcode];
    missPart[mcode * mstride + base + myrank] = i;
  }
  for (int t = tid; t < HB; t += 256) {
    int c = h[t];
    if (c != 0) atomicAdd(&ghist[t], c);
  }
}

// ---------------- K6: fallback — 16-thread group per miss, LDS tiles + hist ------
__global__ void __launch_bounds__(256) k_fallback(
    const float* __restrict__ grid,
    const float4* __restrict__ pC, const int* __restrict__ pSlot,
    const float4* __restrict__ ctr,
    const int* __restrict__ codeCnt,
    const int* __restrict__ missPart, const int* __restrict__ missCnt,
    float* tgt, float* mag, int* ghist, int mstride) {
  __shared__ float4 tile[1024];
  __shared__ int stile[1024];
  __shared__ int h[HB];
  int c = blockIdx.x / FBK;
  int y = blockIdx.x % FBK;
  int mc = missCnt[c];
  if (y * MPB >= mc) return;           // uniform per block
  int cc = codeCnt[c];
  int j0 = c * CSTRIDE;
  const int* mlist = missPart + c * mstride;
  int g = threadIdx.x >> 4;
  int q = threadIdx.x & (GSZ - 1);
  for (int t = threadIdx.x; t < HB; t += 256) h[t] = 0;

  for (int base = y * MPB; base < mc; base += FBK * MPB) {
    int t = base + g;
    bool valid = (t < mc);
    int idx = 0;
    float gx = 0.f, gy = 0.f, gz = 0.f, p2 = 0.f;
    if (valid) {
      idx = mlist[t];
      gx = grid[3*idx]; gy = grid[3*idx+1]; gz = grid[3*idx+2];
      p2 = __fadd_rn(__fadd_rn(__fmul_rn(gx,gx), __fmul_rn(gy,gy)), __fmul_rn(gz,gz));
    }
    unsigned long long key = 0xFFFFFFFFFFFFFFFFULL;
    for (int tb = 0; tb < cc; tb += 1024) {
      int m = min(1024, cc - tb);
      __syncthreads();
      for (int j = threadIdx.x; j < m; j += 256) {
        tile[j] = pC[j0 + tb + j];
        stile[j] = pSlot[j0 + tb + j];
      }
      __syncthreads();
      if (valid) {
        #pragma unroll 4
        for (int j = q; j < m; j += GSZ) {
          float4 cl = tile[j];
          float dot = __fadd_rn(__fadd_rn(__fmul_rn(gx,cl.x), __fmul_rn(gy,cl.y)),
                                __fmul_rn(gz,cl.z));
          float d2 = __fadd_rn(__fsub_rn(p2, __fmul_rn(2.0f, dot)), cl.w);
          unsigned fb = __float_as_uint(d2);
          fb = (fb >> 31) ? ~fb : (fb | 0x80000000u);
          unsigned long long k2 = ((unsigned long long)fb << 32) | (unsigned)stile[j];
          if (k2 < key) key = k2;
        }
      }
    }
    #pragma unroll
    for (int off = 1; off < GSZ; off <<= 1) {
      unsigned long long o = __shfl_xor(key, off, 64);
      if (o < key) key = o;
    }
    if (valid && q == 0) {
      float m = 0.f;
      if (cc > 0) {
        int slot = (int)(unsigned)(key & 0xFFFFFFFFULL);
        float4 cl = ctr[slot];
        tgt[3*idx] = cl.x; tgt[3*idx+1] = cl.y; tgt[3*idx+2] = cl.z;
        float tox = __fsub_rn(cl.x, gx), toy = __fsub_rn(cl.y, gy), toz = __fsub_rn(cl.z, gz);
        float ssq = __fadd_rn(__fadd_rn(__fmul_rn(tox,tox), __fmul_rn(toy,toy)),
                              __fmul_rn(toz,toz));
        m = (ssq > 0.f) ? sqrtf(ssq) : 0.f;
      }
      mag[idx] = m;
      atomicAdd(&h[__float_as_uint(m) >> 21], 1);
    }
    __syncthreads();
  }
  for (int t = threadIdx.x; t < HB; t += 256) {
    int cv = h[t];
    if (cv != 0) atomicAdd(&ghist[t], cv);
  }
}

// ---------------- K7: gather with inlined coarse-bin selection -------------------
__global__ void k_gather(const float* __restrict__ mag, const int* __restrict__ ghist,
                         Scalars* sc, unsigned* bufA, unsigned* bufB, int* cntAB,
                         int n, int r0, int r1) {
  __shared__ int ws[4];
  __shared__ int sBinA, sRA, sBinB, sRB;
  int tid = threadIdx.x, lane = tid & 63, w = tid >> 6;
  int base8 = tid * 8;
  int cbin[8];
  int s = 0;
  #pragma unroll
  for (int k = 0; k < 8; ++k) { cbin[k] = ghist[base8 + k]; s += cbin[k]; }
  int incl = s;
  #pragma unroll
  for (int off = 1; off < 64; off <<= 1) {
    int t = __shfl_up(incl, off, 64);
    if (lane >= off) incl += t;
  }
  if (lane == 63) ws[w] = incl;
  __syncthreads();
  int wofs = 0;
  #pragma unroll
  for (int qq = 0; qq < 4; ++qq) if (qq < w) wofs += ws[qq];
  int lo = wofs + incl - s;
  if (r0 >= lo && r0 < lo + s) {
    int acc = lo;
    #pragma unroll
    for (int k = 0; k < 8; ++k) {
      if (r0 < acc + cbin[k]) { sBinA = base8 + k; sRA = r0 - acc; break; }
      acc += cbin[k];
    }
  }
  if (r1 >= lo && r1 < lo + s) {
    int acc = lo;
    #pragma unroll
    for (int k = 0; k < 8; ++k) {
      if (r1 < acc + cbin[k]) { sBinB = base8 + k; sRB = r1 - acc; break; }
      acc += cbin[k];
    }
  }
  __syncthreads();
  if (blockIdx.x == 0 && tid == 0) {
    sc->binA = sBinA; sc->rA = sRA; sc->binB = sBinB; sc->rB = sRB;
  }
  int binA = sBinA, binB = sBinB;

  int i = blockIdx.x * blockDim.x + tid;
  unsigned bits = 0;
  bool inA = false, inB = false;
  if (i < n) {
    bits = __float_as_uint(mag[i]);
    unsigned cb = bits >> 21;
    inA = (cb == (unsigned)binA);
    inB = (cb == (unsigned)binB);
  }
  {
    unsigned long long mb = __ballot(inA);
    int mc = __popcll(mb);
    int bs = 0;
    if (lane == 0 && mc > 0) bs = atomicAdd(&cntAB[0], mc);
    bs = __shfl(bs, 0, 64);
    if (inA) bufA[bs + __popcll(mb & ((1ULL << lane) - 1ULL))] = bits;
  }
  {
    unsigned long long mb = __ballot(inB);
    int mc = __popcll(mb);
    int bs = 0;
    if (lane == 0 && mc > 0) bs = atomicAdd(&cntAB[1], mc);
    bs = __shfl(bs, 0, 64);
    if (inB) bufB[bs + __popcll(mb & ((1ULL << lane) - 1ULL))] = bits;
  }
}

// ---------------- K7d helper: exact rank select within a coarse bin --------------
__device__ unsigned select_in_bin(const unsigned* __restrict__ buf, int cnt,
                                  int coarse, int rank, int* h, int* ws) {
  __shared__ int sSub, sSubR, sLow;
  for (int t = threadIdx.x; t < HB; t += 1024) h[t] = 0;
  __syncthreads();
  for (int t = threadIdx.x; t < cnt; t += 1024)
    atomicAdd(&h[(buf[t] >> 10) & 0x7FF], 1);
  __syncthreads();
  int t = threadIdx.x;
  int s0 = h[2*t], s1 = h[2*t+1];
  int tot;
  int incl = block_scan_i(s0 + s1, ws, &tot);
  int b1 = incl - s1, b0 = b1 - s0;
  if (rank >= b0 && rank < b0 + s0) { sSub = 2*t;   sSubR = rank - b0; }
  if (rank >= b1 && rank < b1 + s1) { sSub = 2*t+1; sSubR = rank - b1; }
  __syncthreads();
  int subv = sSub, subr = sSubR;
  h[t] = 0;
  __syncthreads();
  for (int q = threadIdx.x; q < cnt; q += 1024) {
    unsigned v = buf[q];
    if ((int)((v >> 10) & 0x7FF) == subv) atomicAdd(&h[v & 0x3FF], 1);
  }
  __syncthreads();
  int c = h[t];
  int tot2;
  int incl2 = block_scan_i(c, ws, &tot2);
  int lb = incl2 - c;
  if (subr >= lb && subr < lb + c) sLow = t;
  __syncthreads();
  return ((unsigned)coarse << 21) | ((unsigned)subv << 10) | (unsigned)sLow;
}

// ---------------- K7d: exact order statistics + lerp (numpy branch) --------------
__global__ void __launch_bounds__(1024) k_sel(const unsigned* __restrict__ bufA,
                                              const unsigned* __restrict__ bufB,
                                              const int* __restrict__ cntAB,
                                              Scalars* sc, double tfrac) {
  __shared__ int h[HB];
  __shared__ int ws[16];
  unsigned va = select_in_bin(bufA, cntAB[0], sc->binA, sc->rA, h, ws);
  __syncthreads();
  unsigned vb = select_in_bin(bufB, cntAB[1], sc->binB, sc->rB, h, ws);
  if (threadIdx.x == 0) {
    double a = (double)__uint_as_float(va);
    double b = (double)__uint_as_float(vb);
    double th = (tfrac >= 0.5) ? (b - (b - a) * (1.0 - tfrac)) : (a + (b - a) * tfrac);
    sc->thresh = (float)th;
  }
}

// ---------------- K8: masked huber + cosine reductions + last-block finalize -----
__global__ void k_loss(const float* __restrict__ pred, const float* __restrict__ grid,
                       const float* __restrict__ tgt, const float* __restrict__ mag,
                       Scalars* sc, float* out, int n) {
  __shared__ double shH[256];
  __shared__ double shC[256];
  __shared__ int shN[256];
  __shared__ int shM[256];
  int tid = threadIdx.x;
  int i = blockIdx.x * blockDim.x + tid;
  double hub = 0.0, cs = 0.0;
  int c1 = 0, cmd = 0;
  if (i < n) {
    float th = sc->thresh;
    float m = mag[i];
    if (m <= th) {
      c1 = 1;
      float tox = __fsub_rn(tgt[3*i],   grid[3*i]);
      float toy = __fsub_rn(tgt[3*i+1], grid[3*i+1]);
      float toz = __fsub_rn(tgt[3*i+2], grid[3*i+2]);
      float px = pred[3*i], py = pred[3*i+1], pz = pred[3*i+2];
      float d0 = __fsub_rn(px, tox), d1 = __fsub_rn(py, toy), d2 = __fsub_rn(pz, toz);
      float a0 = fabsf(d0), a1 = fabsf(d1), a2 = fabsf(d2);
      float h0 = (a0 < 1.f) ? __fmul_rn(__fmul_rn(0.5f, d0), d0) : __fsub_rn(a0, 0.5f);
      float h1 = (a1 < 1.f) ? __fmul_rn(__fmul_rn(0.5f, d1), d1) : __fsub_rn(a1, 0.5f);
      float h2 = (a2 < 1.f) ? __fmul_rn(__fmul_rn(0.5f, d2), d2) : __fsub_rn(a2, 0.5f);
      hub = (double)h0 + (double)h1 + (double)h2;
      if (m > 0.f) {
        cmd = 1;
        float ps = __fadd_rn(__fadd_rn(__fmul_rn(px,px), __fmul_rn(py,py)), __fmul_rn(pz,pz));
        float pn = (ps > 0.f) ? sqrtf(ps) : 0.f;
        float dotp = __fadd_rn(__fadd_rn(__fmul_rn(px,tox), __fmul_rn(py,toy)),
                               __fmul_rn(pz,toz));
        float den = fmaxf(__fmul_rn(pn, m), 1e-4f);
        cs = (double)__fdiv_rn(dotp, den);
      }
    }
  }
  shH[tid] = hub; shC[tid] = cs; shN[tid] = c1; shM[tid] = cmd;
  __syncthreads();
  for (int off = 128; off > 0; off >>= 1) {
    if (tid < off) {
      shH[tid] += shH[tid+off];
      shC[tid] += shC[tid+off];
      shN[tid] += shN[tid+off];
      shM[tid] += shM[tid+off];
    }
    __syncthreads();
  }
  if (tid == 0) {
    atomicAdd(&sc->hub, shH[0]);
    atomicAdd(&sc->cosSum, shC[0]);
    atomicAdd(&sc->n1, shN[0]);
    atomicAdd(&sc->nmd, shM[0]);
    __threadfence();
    int d = atomicAdd(&sc->done, 1);
    if (d == (int)gridDim.x - 1) {
      __threadfence();
      double th_hub = atomicAdd(&sc->hub, 0.0);
      double th_cos = atomicAdd(&sc->cosSum, 0.0);
      int n1 = atomicAdd(&sc->n1, 0);
      int nmd = atomicAdd(&sc->nmd, 0);
      double l1 = (n1 > 0) ? th_hub / fmax((double)n1 * 3.0, 1.0) : 0.0;
      double ld = (nmd > 0) ? (1.0 - th_cos / fmax((double)nmd, 1.0)) : 0.0;
      out[0] = (float)l1;
      out[1] = (float)ld;
    }
  }
}

extern "C" void kernel_launch(void* const* d_in, const int* in_sizes, int n_in,
                              void* d_out, int out_size, void* d_ws, size_t ws_size,
                              hipStream_t stream) {
  const float* pred  = (const float*)d_in[0];
  const float* grid  = (const float*)d_in[1];
  const int*   label = (const int*)d_in[2];
  const int*   batch = (const int*)d_in[3];
  int n = in_sizes[2];
  int mstride = n / 4;

  char* p = (char*)d_ws;
  auto take = [&](size_t bytes) -> char* {
    char* r = p;
    p += (bytes + 255) & ~(size_t)255;
    return r;
  };
  // ---- zero-init region (one hipMemsetAsync covers all of it) ----
  char* zbase = p;
  unsigned long long* vA = (unsigned long long*)take((size_t)SLOTS*8);
  unsigned long long* vB = (unsigned long long*)take((size_t)SLOTS*8);
  int*    lmask    = (int*)   take((size_t)SLOTS*4);
  int*    codeCnt  = (int*)   take(NCODE*4);
  int*    missCnt  = (int*)   take(NCODE*4);
  int*    blCnt    = (int*)   take(16*4);
  float*  blSum    = (float*) take(48*4);
  int*    cntAB    = (int*)   take(2*4);
  int*    ghist    = (int*)   take((size_t)HB*4);
  Scalars* sc      = (Scalars*)take(sizeof(Scalars));
  size_t zbytes = (size_t)(p - zbase);
  // ---- uninitialized buffers ----
  float4* ctr      = (float4*)take((size_t)SLOTS*16);
  float4* pC       = (float4*)take((size_t)NCODE*CSTRIDE*16);
  int*    pSlot    = (int*)   take((size_t)NCODE*CSTRIDE*4);
  unsigned* bufA   = (unsigned*)take((size_t)n*4);
  unsigned* bufB   = (unsigned*)take((size_t)n*4);
  float*  tgt      = (float*) take((size_t)n*3*4);
  float*  mag      = (float*) take((size_t)n*4);
  int*    missPart = (int*)   take((size_t)NCODE*mstride*4);

  int nb = (n + 255) / 256;

  double vi = 0.99 * (double)(n - 1);
  int r0 = (int)vi;
  int r1 = r0 + 1; if (r1 > n - 1) r1 = n - 1;
  double tfrac = vi - (double)r0;

  hipMemsetAsync(zbase, 0, zbytes, stream);
  k_scatter<<<nb, 256, 0, stream>>>(grid, label, batch, vA, vB, lmask,
                                    blCnt, blSum, n);
  k_prep<<<NBLK, 256, 0, stream>>>(vA, vB, lmask, ctr, pC, pSlot, codeCnt);
  k_targets<<<nb, 256, 0, stream>>>(grid, label, batch, ctr, blCnt, blSum,
                                    tgt, mag, ghist, missPart, missCnt, mstride, n);
  k_fallback<<<NCODE * FBK, 256, 0, stream>>>(grid, pC, pSlot, ctr, codeCnt,
                                              missPart, missCnt, tgt, mag, ghist,
                                              mstride);
  k_gather<<<nb, 256, 0, stream>>>(mag, ghist, sc, bufA, bufB, cntAB, n, r0, r1);
  k_sel<<<1, 1024, 0, stream>>>(bufA, bufB, cntAB, sc, tfrac);
  k_loss<<<nb, 256, 0, stream>>>(pred, grid, tgt, mag, sc, (float*)d_out, n);
}